// Round 16
// baseline (60.804 us; speedup 1.0000x reference)
//
#include <hip/hip_runtime.h>
#include <hip/hip_fp16.h>
#include <stdint.h>

#define SEQ 8
#define DIM 16
#define FF 32
#define VOCAB 256
#define TPW 4      // tiles (16 rows each) per wave
#define NFRAG 24   // 8 body fragments + 16 head fragments

typedef _Float16 f16x4 __attribute__((ext_vector_type(4)));
typedef float f32x4 __attribute__((ext_vector_type(4)));

#define SWZF(val, imm) __int_as_float(__builtin_amdgcn_ds_swizzle(__float_as_int(val), (imm)))
#define MFMA(a, b, c) __builtin_amdgcn_mfma_f32_16x16x16f16((a), (b), (c), 0, 0, 0)

__device__ __forceinline__ uint32_t pk2h(float a, float b) {
    return (uint32_t)__half_as_ushort(__float2half(a))
         | ((uint32_t)__half_as_ushort(__float2half(b)) << 16);
}
__device__ __forceinline__ f32x4 splat4(float s) {
    f32x4 r;
    r[0] = s; r[1] = s; r[2] = s; r[3] = s;
    return r;
}
__device__ __forceinline__ f16x4 cvt4(f32x4 a) {
    f16x4 r;
    r[0] = (_Float16)a[0]; r[1] = (_Float16)a[1];
    r[2] = (_Float16)a[2]; r[3] = (_Float16)a[3];
    return r;
}
__device__ __forceinline__ float bperm(int addr, float v) {
    return __int_as_float(__builtin_amdgcn_ds_bpermute(addr, __float_as_int(v)));
}

// ---------------------------------------------------------------------------
// Pack weights into f16 MFMA fragments. Shared per-lane map (validated R11):
//   frag[l] reg i  <->  M[roff + (l>>4)*4 + i][col(l)]
// Body frags f=0..7. Head frags f=8..23 use the PERMUTED vocab mapping:
// frag t = 4*t1+t0, lane col c -> vocab col 4c + t0 + 64*t1 (contiguous
// dwordx4 stores in the head).
// ---------------------------------------------------------------------------
__global__ __launch_bounds__(256) void pack_frags_kernel(
    const float* __restrict__ Wq, const float* __restrict__ Wk,
    const float* __restrict__ Wv, const float* __restrict__ Wo,
    const float* __restrict__ W1, const float* __restrict__ W2,
    const float* __restrict__ Wh, uint64_t* __restrict__ pw)
{
    const int i = blockIdx.x * 256 + threadIdx.x;
    if (i >= NFRAG * 64) return;
    const int f = i >> 6, l = i & 63;
    const int k0 = (l >> 4) * 4, c = l & 15;
    const float* src; int ld, roff, col;
    if      (f == 0) { src = Wq; ld = 16;  roff = 0;  col = c; }
    else if (f == 1) { src = Wk; ld = 16;  roff = 0;  col = c; }
    else if (f == 2) { src = Wv; ld = 16;  roff = 0;  col = c; }
    else if (f == 3) { src = Wo; ld = 16;  roff = 0;  col = c; }
    else if (f == 4) { src = W1; ld = 32;  roff = 0;  col = c; }
    else if (f == 5) { src = W1; ld = 32;  roff = 0;  col = 16 + c; }
    else if (f == 6) { src = W2; ld = 16;  roff = 0;  col = c; }
    else if (f == 7) { src = W2; ld = 16;  roff = 16; col = c; }
    else {
        const int t = f - 8;
        src = Wh; ld = 256; roff = 0;
        col = 4 * c + (t & 3) + 64 * (t >> 2);
    }
    const uint32_t lo = pk2h(src[(roff + k0 + 0) * ld + col],
                             src[(roff + k0 + 1) * ld + col]);
    const uint32_t hi = pk2h(src[(roff + k0 + 2) * ld + col],
                             src[(roff + k0 + 3) * ld + col]);
    pw[i] = (uint64_t)lo | ((uint64_t)hi << 32);
}

// ---------------------------------------------------------------------------
// Fused transformer: 1 wave = one 16-row tile (2 seq-items) end-to-end.
// R16 = R14 (proven best, 54.06us) + ONE change: non-temporal head stores
// (hypothesis: L2 write-allocate tax on 262MB streaming writes).
// ---------------------------------------------------------------------------
__global__ __launch_bounds__(256) void fused_mfma_kernel(
    const int* __restrict__ x,
    const float* __restrict__ te, const float* __restrict__ pe,
    const float* __restrict__ bq, const float* __restrict__ bk,
    const float* __restrict__ bv, const float* __restrict__ bo,
    const float* __restrict__ b1, const float* __restrict__ b2,
    const float* __restrict__ bh,
    const f16x4* __restrict__ pw,
    float* __restrict__ out)
{
    __shared__ float xls[4][320];   // per-wave [16][20] f32 transpose buffer

    const int tid = threadIdx.x;
    const int wv = tid >> 6, l = tid & 63;
    const int g = l >> 4, c = l & 15, k0 = g * 4;

    // fragments (once)
    const f16x4 Fq  = pw[0 * 64 + l], Fk  = pw[1 * 64 + l];
    const f16x4 Fv  = pw[2 * 64 + l], Fo  = pw[3 * 64 + l];
    const f16x4 F1a = pw[4 * 64 + l], F1b = pw[5 * 64 + l];
    const f16x4 F2a = pw[6 * 64 + l], F2b = pw[7 * 64 + l];
    f16x4 Fh[16];
    #pragma unroll
    for (int t = 0; t < 16; ++t) Fh[t] = pw[(8 + t) * 64 + l];

    // biases (once)
    const f32x4 bq4  = *(const f32x4*)(bq + k0);
    const f32x4 bk4  = *(const f32x4*)(bk + k0);
    const f32x4 bv4  = splat4(bv[c]);
    const f32x4 bo4  = splat4(bo[c]);
    const f32x4 b1a4 = *(const f32x4*)(b1 + k0);
    const f32x4 b1b4 = *(const f32x4*)(b1 + 16 + k0);
    const f32x4 b24  = *(const f32x4*)(b2 + k0);
    float bhv[16];
    #pragma unroll
    for (int t = 0; t < 16; ++t)
        bhv[t] = bh[4 * c + (t & 3) + 64 * (t >> 2)];   // permuted vocab map

    // positional rows (once; tile row base is a multiple of 16)
    const f32x4 peA = *(const f32x4*)(pe + (l & 7) * 16 + k0);
    float peD[4];
    #pragma unroll
    for (int j = 0; j < 4; ++j) peD[j] = pe[((k0 + j) & 7) * 16 + c];

    // softmax helpers: valid iff this lane-group's keyrows belong to col c's item
    const bool keep = ((g >> 1) == (c >> 3));
    const int bpaddr = 4 * (32 * (c >> 3) + c);   // lane holding col c's valid pair-sum
    float* myl = xls[wv];
    const f32x4 zero = splat4(0.f);

    for (int tt = 0; tt < TPW; ++tt) {
        const int tile = blockIdx.x * (4 * TPW) + wv * TPW + tt;
        const int r0 = tile * 16;

        // ---- X in A-layout (f16) and D-layout (f32, for residual) ----
        f16x4 Xf;
        {
            const int idxA = x[r0 + c];
            const f32x4 teA = *(const f32x4*)(te + idxA * DIM + k0);
            f32x4 xa = teA + peA;
            Xf = cvt4(xa);
        }
        f32x4 XD;
        #pragma unroll
        for (int j = 0; j < 4; ++j) {
            const int idxD = x[r0 + k0 + j];
            XD[j] = te[idxD * DIM + c] + peD[j];
        }

        // ---- QKV (bias in C-init; 0.25 folded into Q) ----
        f32x4 qa = MFMA(Fq, Xf, bq4);          // Q^T
        f32x4 ka = MFMA(Fk, Xf, bk4);          // K^T
        f32x4 va = MFMA(Xf, Fv, bv4);          // V
        f16x4 Qf, Kf, Vf;
        #pragma unroll
        for (int j = 0; j < 4; ++j) {
            Qf[j] = (_Float16)(qa[j] * 0.25f);
            Kf[j] = (_Float16)ka[j];
            Vf[j] = (_Float16)va[j];
        }

        // ---- S^T = K @ Q^T, masked softmax over keyrows (rows of S^T) ----
        f32x4 s = MFMA(Kf, Qf, zero);
        #pragma unroll
        for (int j = 0; j < 4; ++j) s[j] = keep ? s[j] : -1e30f;
        float m0 = fmaxf(fmaxf(s[0], s[1]), fmaxf(s[2], s[3]));
        m0 = fmaxf(m0, SWZF(m0, 0x401F));            // pair (xor 16)
        const float mx = bperm(bpaddr, m0);          // broadcast valid pair
        f32x4 p;
        #pragma unroll
        for (int j = 0; j < 4; ++j) p[j] = __expf(s[j] - mx);  // masked -> 0
        float s0 = p[0] + p[1] + p[2] + p[3];
        s0 += SWZF(s0, 0x401F);
        const float inv = 1.0f / bperm(bpaddr, s0);
        const f16x4 Pf = cvt4(p);                    // P^T, unnormalized

        // ---- attn^T = V^T @ P^T (post-normalized) ----
        f32x4 att = MFMA(Vf, Pf, zero);
        #pragma unroll
        for (int j = 0; j < 4; ++j) att[j] *= inv;
        const f16x4 Af = cvt4(att);                  // = attn in A-layout

        // ---- X1 = attn @ Wo + bo + X (D-layout f32) ----
        f32x4 x1 = MFMA(Af, Fo, bo4);
        x1 += XD;

        // ---- transpose X1 via LDS (per-wave buffer, no barrier) ----
        #pragma unroll
        for (int j = 0; j < 4; ++j) myl[(k0 + j) * 20 + c] = x1[j];
        const f32x4 x1t = *(const f32x4*)(myl + c * 20 + k0);  // X1 A-map, f32
        const f16x4 X1f = cvt4(x1t);

        // ---- FFN (transposed): H^T = W1^T @ X1^T, X2^T = W2^T @ H^T ----
        f32x4 ha = MFMA(F1a, X1f, b1a4);
        f32x4 hb = MFMA(F1b, X1f, b1b4);
        #pragma unroll
        for (int j = 0; j < 4; ++j) {
            ha[j] = fmaxf(ha[j], 0.f);
            hb[j] = fmaxf(hb[j], 0.f);
        }
        const f16x4 Haf = cvt4(ha), Hbf = cvt4(hb);
        f32x4 x2 = b24 + x1t;                        // residual + b2
        x2 = MFMA(F2a, Haf, x2);
        x2 = MFMA(F2b, Hbf, x2);
        const f16x4 X2f = cvt4(x2);                  // = X2 in A-layout

        // ---- head: logits = X2 @ Wh + bh, contiguous NT dwordx4 stores ----
        // frag t=4*t1+t0, lane col c -> vocab col 4c + t0 + 64*t1.
        #pragma unroll
        for (int t1 = 0; t1 < 4; ++t1) {
            f32x4 o0 = MFMA(X2f, Fh[4 * t1 + 0], splat4(bhv[4 * t1 + 0]));
            f32x4 o1 = MFMA(X2f, Fh[4 * t1 + 1], splat4(bhv[4 * t1 + 1]));
            f32x4 o2 = MFMA(X2f, Fh[4 * t1 + 2], splat4(bhv[4 * t1 + 2]));
            f32x4 o3 = MFMA(X2f, Fh[4 * t1 + 3], splat4(bhv[4 * t1 + 3]));
            #pragma unroll
            for (int j = 0; j < 4; ++j) {
                f32x4 st;
                st[0] = o0[j]; st[1] = o1[j]; st[2] = o2[j]; st[3] = o3[j];
                __builtin_nontemporal_store(
                    st, (f32x4*)(out + (size_t)(r0 + k0 + j) * VOCAB + 64 * t1 + 4 * c));
            }
        }
    }
}

// ---------------------------------------------------------------------------
// Fallback (ws too small): single-pass per-row body + per-column head.
// ---------------------------------------------------------------------------
#define ITEMS_PER_BLOCK 32
#define ITEM_STRIDE 136

__global__ __launch_bounds__(256) void fused_fallback_kernel(
    const int* __restrict__ x,
    const float* __restrict__ token_embed,
    const float* __restrict__ pos_embed,
    const float* __restrict__ Wq, const float* __restrict__ bq,
    const float* __restrict__ Wk, const float* __restrict__ bk,
    const float* __restrict__ Wv, const float* __restrict__ bv,
    const float* __restrict__ Wo, const float* __restrict__ bo,
    const float* __restrict__ W1, const float* __restrict__ b1,
    const float* __restrict__ W2, const float* __restrict__ b2,
    const float* __restrict__ Wh, const float* __restrict__ bh,
    float* __restrict__ out)
{
    __shared__ float sK[ITEMS_PER_BLOCK * ITEM_STRIDE];
    __shared__ float sV[ITEMS_PER_BLOCK * ITEM_STRIDE];

    const int tid = threadIdx.x;
    const int i = tid >> 3;
    const int n = tid & 7;
    const int b = blockIdx.x * ITEMS_PER_BLOCK + i;

    float X[DIM];
    {
        const int idx = x[b * SEQ + n];
        const float4* te4 = (const float4*)(token_embed + idx * DIM);
        const float4* pe4 = (const float4*)(pos_embed + n * DIM);
        #pragma unroll
        for (int j = 0; j < 4; ++j) {
            float4 a = te4[j];
            float4 p = pe4[j];
            X[4*j+0] = a.x + p.x; X[4*j+1] = a.y + p.y;
            X[4*j+2] = a.z + p.z; X[4*j+3] = a.w + p.w;
        }
    }

    float Q[DIM], Kr[DIM], Vr[DIM];
    #pragma unroll
    for (int e = 0; e < DIM; ++e) {
        float qq = bq[e], kk = bk[e], vv = bv[e];
        #pragma unroll
        for (int d = 0; d < DIM; ++d) {
            qq += X[d] * Wq[d * DIM + e];
            kk += X[d] * Wk[d * DIM + e];
            vv += X[d] * Wv[d * DIM + e];
        }
        Q[e] = qq; Kr[e] = kk; Vr[e] = vv;
    }
    {
        float* kdst = sK + i * ITEM_STRIDE + n * DIM;
        float* vdst = sV + i * ITEM_STRIDE + n * DIM;
        #pragma unroll
        for (int j = 0; j < 4; ++j) {
            float4 kk, vv;
            kk.x = Kr[4*j+0]; kk.y = Kr[4*j+1]; kk.z = Kr[4*j+2]; kk.w = Kr[4*j+3];
            vv.x = Vr[4*j+0]; vv.y = Vr[4*j+1]; vv.z = Vr[4*j+2]; vv.w = Vr[4*j+3];
            ((float4*)kdst)[j] = kk;
            ((float4*)vdst)[j] = vv;
        }
    }
    __syncthreads();

    float sc[SEQ];
    #pragma unroll
    for (int m = 0; m < SEQ; ++m) {
        const float* kr = sK + i * ITEM_STRIDE + m * DIM;
        float s = 0.f;
        #pragma unroll
        for (int d = 0; d < DIM; ++d) s += Q[d] * kr[d];
        sc[m] = s * 0.25f;
    }
    float mx = sc[0];
    #pragma unroll
    for (int m = 1; m < SEQ; ++m) mx = fmaxf(mx, sc[m]);
    float sum = 0.f;
    #pragma unroll
    for (int m = 0; m < SEQ; ++m) { sc[m] = __expf(sc[m] - mx); sum += sc[m]; }
    const float inv = 1.0f / sum;

    float at[DIM];
    #pragma unroll
    for (int d = 0; d < DIM; ++d) at[d] = 0.f;
    #pragma unroll
    for (int m = 0; m < SEQ; ++m) {
        const float w = sc[m] * inv;
        const float* vr = sV + i * ITEM_STRIDE + m * DIM;
        #pragma unroll
        for (int d = 0; d < DIM; ++d) at[d] += w * vr[d];
    }

    float X1[DIM];
    #pragma unroll
    for (int e = 0; e < DIM; ++e) {
        float o = bo[e];
        #pragma unroll
        for (int d = 0; d < DIM; ++d) o += at[d] * Wo[d * DIM + e];
        X1[e] = X[e] + o;
    }
    float h[FF];
    #pragma unroll
    for (int f = 0; f < FF; ++f) {
        float a = b1[f];
        #pragma unroll
        for (int d = 0; d < DIM; ++d) a += X1[d] * W1[d * FF + f];
        h[f] = fmaxf(a, 0.f);
    }
    float X2[DIM];
    #pragma unroll
    for (int e = 0; e < DIM; ++e) {
        float a = b2[e];
        #pragma unroll
        for (int f = 0; f < FF; ++f) a += h[f] * W2[f * DIM + e];
        X2[e] = X1[e] + a;
    }

    __syncthreads();
    {
        float* xdst = sK + i * ITEM_STRIDE + n * DIM;
        #pragma unroll
        for (int j = 0; j < 4; ++j) {
            float4 xx;
            xx.x = X2[4*j+0]; xx.y = X2[4*j+1]; xx.z = X2[4*j+2]; xx.w = X2[4*j+3];
            ((float4*)xdst)[j] = xx;
        }
    }
    __syncthreads();

    float wh[DIM];
    #pragma unroll
    for (int d = 0; d < DIM; ++d) wh[d] = Wh[d * VOCAB + tid];
    const float bhv = bh[tid];

    const size_t obase = (size_t)blockIdx.x * (ITEMS_PER_BLOCK * SEQ) * VOCAB + tid;
    #pragma unroll 4
    for (int r = 0; r < ITEMS_PER_BLOCK * SEQ; ++r) {
        const float* xr = sK + (r >> 3) * ITEM_STRIDE + (r & 7) * DIM;
        float acc = bhv;
        #pragma unroll
        for (int d = 0; d < DIM; ++d) acc += xr[d] * wh[d];
        out[obase + (size_t)r * VOCAB] = acc;
    }
}

extern "C" void kernel_launch(void* const* d_in, const int* in_sizes, int n_in,
                              void* d_out, int out_size, void* d_ws, size_t ws_size,
                              hipStream_t stream) {
    const int*   x           = (const int*)  d_in[0];
    const float* token_embed = (const float*)d_in[1];
    const float* pos_embed   = (const float*)d_in[2];
    const float* Wq = (const float*)d_in[3];
    const float* bq = (const float*)d_in[4];
    const float* Wk = (const float*)d_in[5];
    const float* bk = (const float*)d_in[6];
    const float* Wv = (const float*)d_in[7];
    const float* bv = (const float*)d_in[8];
    const float* Wo = (const float*)d_in[9];
    const float* bo = (const float*)d_in[10];
    const float* W1 = (const float*)d_in[11];
    const float* b1 = (const float*)d_in[12];
    const float* W2 = (const float*)d_in[13];
    const float* b2 = (const float*)d_in[14];
    const float* Wh = (const float*)d_in[15];
    const float* bh = (const float*)d_in[16];
    float* out = (float*)d_out;

    const int B = in_sizes[0] / SEQ;                 // 32768
    const int nrows = B * SEQ;                       // 262144
    const int ntiles = nrows / 16;                   // 16384
    const size_t ws_needed = (size_t)NFRAG * 64 * 8; // 12 KB

    if (ws_size >= ws_needed) {
        uint64_t* pw = (uint64_t*)d_ws;
        pack_frags_kernel<<<(NFRAG * 64 + 255) / 256, 256, 0, stream>>>(
            Wq, Wk, Wv, Wo, W1, W2, Wh, pw);
        fused_mfma_kernel<<<ntiles / (4 * TPW), 256, 0, stream>>>(
            x, token_embed, pos_embed, bq, bk, bv, bo, b1, b2, bh,
            (const f16x4*)pw, out);
    } else {
        fused_fallback_kernel<<<B / ITEMS_PER_BLOCK, 256, 0, stream>>>(
            x, token_embed, pos_embed, Wq, bq, Wk, bk, Wv, bv, Wo, bo,
            W1, b1, W2, b2, Wh, bh, out);
    }
}

// Round 17
// 53.268 us; speedup vs baseline: 1.1415x; 1.1415x over previous
//
#include <hip/hip_runtime.h>
#include <hip/hip_fp16.h>
#include <stdint.h>

#define SEQ 8
#define DIM 16
#define FF 32
#define VOCAB 256
#define TPW 4      // tiles (16 rows each) per wave
#define NFRAG 24   // 8 body fragments + 16 head fragments

typedef _Float16 f16x4 __attribute__((ext_vector_type(4)));
typedef float f32x4 __attribute__((ext_vector_type(4)));

#define SWZF(val, imm) __int_as_float(__builtin_amdgcn_ds_swizzle(__float_as_int(val), (imm)))
#define MFMA(a, b, c) __builtin_amdgcn_mfma_f32_16x16x16f16((a), (b), (c), 0, 0, 0)

__device__ __forceinline__ uint32_t pk2h(float a, float b) {
    return (uint32_t)__half_as_ushort(__float2half(a))
         | ((uint32_t)__half_as_ushort(__float2half(b)) << 16);
}
__device__ __forceinline__ f32x4 splat4(float s) {
    f32x4 r;
    r[0] = s; r[1] = s; r[2] = s; r[3] = s;
    return r;
}
__device__ __forceinline__ f16x4 cvt4(f32x4 a) {
    f16x4 r;
    r[0] = (_Float16)a[0]; r[1] = (_Float16)a[1];
    r[2] = (_Float16)a[2]; r[3] = (_Float16)a[3];
    return r;
}
__device__ __forceinline__ float bperm(int addr, float v) {
    return __int_as_float(__builtin_amdgcn_ds_bpermute(addr, __float_as_int(v)));
}

// ---------------------------------------------------------------------------
// Pack weights into f16 MFMA fragments. Shared per-lane map (validated R11):
//   frag[l] reg i  <->  M[roff + (l>>4)*4 + i][col(l)]
// Body frags f=0..7. Head frags f=8..23 use the PERMUTED vocab mapping:
// frag t = 4*t1+t0, lane col c -> vocab col 4c + t0 + 64*t1 (contiguous
// dwordx4 stores in the head).
// ---------------------------------------------------------------------------
__global__ __launch_bounds__(256) void pack_frags_kernel(
    const float* __restrict__ Wq, const float* __restrict__ Wk,
    const float* __restrict__ Wv, const float* __restrict__ Wo,
    const float* __restrict__ W1, const float* __restrict__ W2,
    const float* __restrict__ Wh, uint64_t* __restrict__ pw)
{
    const int i = blockIdx.x * 256 + threadIdx.x;
    if (i >= NFRAG * 64) return;
    const int f = i >> 6, l = i & 63;
    const int k0 = (l >> 4) * 4, c = l & 15;
    const float* src; int ld, roff, col;
    if      (f == 0) { src = Wq; ld = 16;  roff = 0;  col = c; }
    else if (f == 1) { src = Wk; ld = 16;  roff = 0;  col = c; }
    else if (f == 2) { src = Wv; ld = 16;  roff = 0;  col = c; }
    else if (f == 3) { src = Wo; ld = 16;  roff = 0;  col = c; }
    else if (f == 4) { src = W1; ld = 32;  roff = 0;  col = c; }
    else if (f == 5) { src = W1; ld = 32;  roff = 0;  col = 16 + c; }
    else if (f == 6) { src = W2; ld = 16;  roff = 0;  col = c; }
    else if (f == 7) { src = W2; ld = 16;  roff = 16; col = c; }
    else {
        const int t = f - 8;
        src = Wh; ld = 256; roff = 0;
        col = 4 * c + (t & 3) + 64 * (t >> 2);
    }
    const uint32_t lo = pk2h(src[(roff + k0 + 0) * ld + col],
                             src[(roff + k0 + 1) * ld + col]);
    const uint32_t hi = pk2h(src[(roff + k0 + 2) * ld + col],
                             src[(roff + k0 + 3) * ld + col]);
    pw[i] = (uint64_t)lo | ((uint64_t)hi << 32);
}

// ---------------------------------------------------------------------------
// Fused transformer: 1 wave = one 16-row tile (2 seq-items) end-to-end.
// R17 = exact revert to R14 (proven best, 54.06us): regular stores, TPW=4,
// VGPR-resident Fh, permuted contiguous dwordx4 head stores.
// ---------------------------------------------------------------------------
__global__ __launch_bounds__(256) void fused_mfma_kernel(
    const int* __restrict__ x,
    const float* __restrict__ te, const float* __restrict__ pe,
    const float* __restrict__ bq, const float* __restrict__ bk,
    const float* __restrict__ bv, const float* __restrict__ bo,
    const float* __restrict__ b1, const float* __restrict__ b2,
    const float* __restrict__ bh,
    const f16x4* __restrict__ pw,
    float* __restrict__ out)
{
    __shared__ float xls[4][320];   // per-wave [16][20] f32 transpose buffer

    const int tid = threadIdx.x;
    const int wv = tid >> 6, l = tid & 63;
    const int g = l >> 4, c = l & 15, k0 = g * 4;

    // fragments (once)
    const f16x4 Fq  = pw[0 * 64 + l], Fk  = pw[1 * 64 + l];
    const f16x4 Fv  = pw[2 * 64 + l], Fo  = pw[3 * 64 + l];
    const f16x4 F1a = pw[4 * 64 + l], F1b = pw[5 * 64 + l];
    const f16x4 F2a = pw[6 * 64 + l], F2b = pw[7 * 64 + l];
    f16x4 Fh[16];
    #pragma unroll
    for (int t = 0; t < 16; ++t) Fh[t] = pw[(8 + t) * 64 + l];

    // biases (once)
    const f32x4 bq4  = *(const f32x4*)(bq + k0);
    const f32x4 bk4  = *(const f32x4*)(bk + k0);
    const f32x4 bv4  = splat4(bv[c]);
    const f32x4 bo4  = splat4(bo[c]);
    const f32x4 b1a4 = *(const f32x4*)(b1 + k0);
    const f32x4 b1b4 = *(const f32x4*)(b1 + 16 + k0);
    const f32x4 b24  = *(const f32x4*)(b2 + k0);
    float bhv[16];
    #pragma unroll
    for (int t = 0; t < 16; ++t)
        bhv[t] = bh[4 * c + (t & 3) + 64 * (t >> 2)];   // permuted vocab map

    // positional rows (once; tile row base is a multiple of 16)
    const f32x4 peA = *(const f32x4*)(pe + (l & 7) * 16 + k0);
    float peD[4];
    #pragma unroll
    for (int j = 0; j < 4; ++j) peD[j] = pe[((k0 + j) & 7) * 16 + c];

    // softmax helpers: valid iff this lane-group's keyrows belong to col c's item
    const bool keep = ((g >> 1) == (c >> 3));
    const int bpaddr = 4 * (32 * (c >> 3) + c);   // lane holding col c's valid pair-sum
    float* myl = xls[wv];
    const f32x4 zero = splat4(0.f);

    for (int tt = 0; tt < TPW; ++tt) {
        const int tile = blockIdx.x * (4 * TPW) + wv * TPW + tt;
        const int r0 = tile * 16;

        // ---- X in A-layout (f16) and D-layout (f32, for residual) ----
        f16x4 Xf;
        {
            const int idxA = x[r0 + c];
            const f32x4 teA = *(const f32x4*)(te + idxA * DIM + k0);
            f32x4 xa = teA + peA;
            Xf = cvt4(xa);
        }
        f32x4 XD;
        #pragma unroll
        for (int j = 0; j < 4; ++j) {
            const int idxD = x[r0 + k0 + j];
            XD[j] = te[idxD * DIM + c] + peD[j];
        }

        // ---- QKV (bias in C-init; 0.25 folded into Q) ----
        f32x4 qa = MFMA(Fq, Xf, bq4);          // Q^T
        f32x4 ka = MFMA(Fk, Xf, bk4);          // K^T
        f32x4 va = MFMA(Xf, Fv, bv4);          // V
        f16x4 Qf, Kf, Vf;
        #pragma unroll
        for (int j = 0; j < 4; ++j) {
            Qf[j] = (_Float16)(qa[j] * 0.25f);
            Kf[j] = (_Float16)ka[j];
            Vf[j] = (_Float16)va[j];
        }

        // ---- S^T = K @ Q^T, masked softmax over keyrows (rows of S^T) ----
        f32x4 s = MFMA(Kf, Qf, zero);
        #pragma unroll
        for (int j = 0; j < 4; ++j) s[j] = keep ? s[j] : -1e30f;
        float m0 = fmaxf(fmaxf(s[0], s[1]), fmaxf(s[2], s[3]));
        m0 = fmaxf(m0, SWZF(m0, 0x401F));            // pair (xor 16)
        const float mx = bperm(bpaddr, m0);          // broadcast valid pair
        f32x4 p;
        #pragma unroll
        for (int j = 0; j < 4; ++j) p[j] = __expf(s[j] - mx);  // masked -> 0
        float s0 = p[0] + p[1] + p[2] + p[3];
        s0 += SWZF(s0, 0x401F);
        const float inv = 1.0f / bperm(bpaddr, s0);
        const f16x4 Pf = cvt4(p);                    // P^T, unnormalized

        // ---- attn^T = V^T @ P^T (post-normalized) ----
        f32x4 att = MFMA(Vf, Pf, zero);
        #pragma unroll
        for (int j = 0; j < 4; ++j) att[j] *= inv;
        const f16x4 Af = cvt4(att);                  // = attn in A-layout

        // ---- X1 = attn @ Wo + bo + X (D-layout f32) ----
        f32x4 x1 = MFMA(Af, Fo, bo4);
        x1 += XD;

        // ---- transpose X1 via LDS (per-wave buffer, no barrier) ----
        #pragma unroll
        for (int j = 0; j < 4; ++j) myl[(k0 + j) * 20 + c] = x1[j];
        const f32x4 x1t = *(const f32x4*)(myl + c * 20 + k0);  // X1 A-map, f32
        const f16x4 X1f = cvt4(x1t);

        // ---- FFN (transposed): H^T = W1^T @ X1^T, X2^T = W2^T @ H^T ----
        f32x4 ha = MFMA(F1a, X1f, b1a4);
        f32x4 hb = MFMA(F1b, X1f, b1b4);
        #pragma unroll
        for (int j = 0; j < 4; ++j) {
            ha[j] = fmaxf(ha[j], 0.f);
            hb[j] = fmaxf(hb[j], 0.f);
        }
        const f16x4 Haf = cvt4(ha), Hbf = cvt4(hb);
        f32x4 x2 = b24 + x1t;                        // residual + b2
        x2 = MFMA(F2a, Haf, x2);
        x2 = MFMA(F2b, Hbf, x2);
        const f16x4 X2f = cvt4(x2);                  // = X2 in A-layout

        // ---- head: logits = X2 @ Wh + bh, contiguous dwordx4 stores ----
        // frag t=4*t1+t0, lane col c -> vocab col 4c + t0 + 64*t1.
        #pragma unroll
        for (int t1 = 0; t1 < 4; ++t1) {
            f32x4 o0 = MFMA(X2f, Fh[4 * t1 + 0], splat4(bhv[4 * t1 + 0]));
            f32x4 o1 = MFMA(X2f, Fh[4 * t1 + 1], splat4(bhv[4 * t1 + 1]));
            f32x4 o2 = MFMA(X2f, Fh[4 * t1 + 2], splat4(bhv[4 * t1 + 2]));
            f32x4 o3 = MFMA(X2f, Fh[4 * t1 + 3], splat4(bhv[4 * t1 + 3]));
            #pragma unroll
            for (int j = 0; j < 4; ++j) {
                f32x4 st;
                st[0] = o0[j]; st[1] = o1[j]; st[2] = o2[j]; st[3] = o3[j];
                *(f32x4*)(out + (size_t)(r0 + k0 + j) * VOCAB + 64 * t1 + 4 * c) = st;
            }
        }
    }
}

// ---------------------------------------------------------------------------
// Fallback (ws too small): single-pass per-row body + per-column head.
// ---------------------------------------------------------------------------
#define ITEMS_PER_BLOCK 32
#define ITEM_STRIDE 136

__global__ __launch_bounds__(256) void fused_fallback_kernel(
    const int* __restrict__ x,
    const float* __restrict__ token_embed,
    const float* __restrict__ pos_embed,
    const float* __restrict__ Wq, const float* __restrict__ bq,
    const float* __restrict__ Wk, const float* __restrict__ bk,
    const float* __restrict__ Wv, const float* __restrict__ bv,
    const float* __restrict__ Wo, const float* __restrict__ bo,
    const float* __restrict__ W1, const float* __restrict__ b1,
    const float* __restrict__ W2, const float* __restrict__ b2,
    const float* __restrict__ Wh, const float* __restrict__ bh,
    float* __restrict__ out)
{
    __shared__ float sK[ITEMS_PER_BLOCK * ITEM_STRIDE];
    __shared__ float sV[ITEMS_PER_BLOCK * ITEM_STRIDE];

    const int tid = threadIdx.x;
    const int i = tid >> 3;
    const int n = tid & 7;
    const int b = blockIdx.x * ITEMS_PER_BLOCK + i;

    float X[DIM];
    {
        const int idx = x[b * SEQ + n];
        const float4* te4 = (const float4*)(token_embed + idx * DIM);
        const float4* pe4 = (const float4*)(pos_embed + n * DIM);
        #pragma unroll
        for (int j = 0; j < 4; ++j) {
            float4 a = te4[j];
            float4 p = pe4[j];
            X[4*j+0] = a.x + p.x; X[4*j+1] = a.y + p.y;
            X[4*j+2] = a.z + p.z; X[4*j+3] = a.w + p.w;
        }
    }

    float Q[DIM], Kr[DIM], Vr[DIM];
    #pragma unroll
    for (int e = 0; e < DIM; ++e) {
        float qq = bq[e], kk = bk[e], vv = bv[e];
        #pragma unroll
        for (int d = 0; d < DIM; ++d) {
            qq += X[d] * Wq[d * DIM + e];
            kk += X[d] * Wk[d * DIM + e];
            vv += X[d] * Wv[d * DIM + e];
        }
        Q[e] = qq; Kr[e] = kk; Vr[e] = vv;
    }
    {
        float* kdst = sK + i * ITEM_STRIDE + n * DIM;
        float* vdst = sV + i * ITEM_STRIDE + n * DIM;
        #pragma unroll
        for (int j = 0; j < 4; ++j) {
            float4 kk, vv;
            kk.x = Kr[4*j+0]; kk.y = Kr[4*j+1]; kk.z = Kr[4*j+2]; kk.w = Kr[4*j+3];
            vv.x = Vr[4*j+0]; vv.y = Vr[4*j+1]; vv.z = Vr[4*j+2]; vv.w = Vr[4*j+3];
            ((float4*)kdst)[j] = kk;
            ((float4*)vdst)[j] = vv;
        }
    }
    __syncthreads();

    float sc[SEQ];
    #pragma unroll
    for (int m = 0; m < SEQ; ++m) {
        const float* kr = sK + i * ITEM_STRIDE + m * DIM;
        float s = 0.f;
        #pragma unroll
        for (int d = 0; d < DIM; ++d) s += Q[d] * kr[d];
        sc[m] = s * 0.25f;
    }
    float mx = sc[0];
    #pragma unroll
    for (int m = 1; m < SEQ; ++m) mx = fmaxf(mx, sc[m]);
    float sum = 0.f;
    #pragma unroll
    for (int m = 0; m < SEQ; ++m) { sc[m] = __expf(sc[m] - mx); sum += sc[m]; }
    const float inv = 1.0f / sum;

    float at[DIM];
    #pragma unroll
    for (int d = 0; d < DIM; ++d) at[d] = 0.f;
    #pragma unroll
    for (int m = 0; m < SEQ; ++m) {
        const float w = sc[m] * inv;
        const float* vr = sV + i * ITEM_STRIDE + m * DIM;
        #pragma unroll
        for (int d = 0; d < DIM; ++d) at[d] += w * vr[d];
    }

    float X1[DIM];
    #pragma unroll
    for (int e = 0; e < DIM; ++e) {
        float o = bo[e];
        #pragma unroll
        for (int d = 0; d < DIM; ++d) o += at[d] * Wo[d * DIM + e];
        X1[e] = X[e] + o;
    }
    float h[FF];
    #pragma unroll
    for (int f = 0; f < FF; ++f) {
        float a = b1[f];
        #pragma unroll
        for (int d = 0; d < DIM; ++d) a += X1[d] * W1[d * FF + f];
        h[f] = fmaxf(a, 0.f);
    }
    float X2[DIM];
    #pragma unroll
    for (int e = 0; e < DIM; ++e) {
        float a = b2[e];
        #pragma unroll
        for (int f = 0; f < FF; ++f) a += h[f] * W2[f * DIM + e];
        X2[e] = X1[e] + a;
    }

    __syncthreads();
    {
        float* xdst = sK + i * ITEM_STRIDE + n * DIM;
        #pragma unroll
        for (int j = 0; j < 4; ++j) {
            float4 xx;
            xx.x = X2[4*j+0]; xx.y = X2[4*j+1]; xx.z = X2[4*j+2]; xx.w = X2[4*j+3];
            ((float4*)xdst)[j] = xx;
        }
    }
    __syncthreads();

    float wh[DIM];
    #pragma unroll
    for (int d = 0; d < DIM; ++d) wh[d] = Wh[d * VOCAB + tid];
    const float bhv = bh[tid];

    const size_t obase = (size_t)blockIdx.x * (ITEMS_PER_BLOCK * SEQ) * VOCAB + tid;
    #pragma unroll 4
    for (int r = 0; r < ITEMS_PER_BLOCK * SEQ; ++r) {
        const float* xr = sK + (r >> 3) * ITEM_STRIDE + (r & 7) * DIM;
        float acc = bhv;
        #pragma unroll
        for (int d = 0; d < DIM; ++d) acc += xr[d] * wh[d];
        out[obase + (size_t)r * VOCAB] = acc;
    }
}

extern "C" void kernel_launch(void* const* d_in, const int* in_sizes, int n_in,
                              void* d_out, int out_size, void* d_ws, size_t ws_size,
                              hipStream_t stream) {
    const int*   x           = (const int*)  d_in[0];
    const float* token_embed = (const float*)d_in[1];
    const float* pos_embed   = (const float*)d_in[2];
    const float* Wq = (const float*)d_in[3];
    const float* bq = (const float*)d_in[4];
    const float* Wk = (const float*)d_in[5];
    const float* bk = (const float*)d_in[6];
    const float* Wv = (const float*)d_in[7];
    const float* bv = (const float*)d_in[8];
    const float* Wo = (const float*)d_in[9];
    const float* bo = (const float*)d_in[10];
    const float* W1 = (const float*)d_in[11];
    const float* b1 = (const float*)d_in[12];
    const float* W2 = (const float*)d_in[13];
    const float* b2 = (const float*)d_in[14];
    const float* Wh = (const float*)d_in[15];
    const float* bh = (const float*)d_in[16];
    float* out = (float*)d_out;

    const int B = in_sizes[0] / SEQ;                 // 32768
    const int nrows = B * SEQ;                       // 262144
    const int ntiles = nrows / 16;                   // 16384
    const size_t ws_needed = (size_t)NFRAG * 64 * 8; // 12 KB

    if (ws_size >= ws_needed) {
        uint64_t* pw = (uint64_t*)d_ws;
        pack_frags_kernel<<<(NFRAG * 64 + 255) / 256, 256, 0, stream>>>(
            Wq, Wk, Wv, Wo, W1, W2, Wh, pw);
        fused_mfma_kernel<<<ntiles / (4 * TPW), 256, 0, stream>>>(
            x, token_embed, pos_embed, bq, bk, bv, bo, b1, b2, bh,
            (const f16x4*)pw, out);
    } else {
        fused_fallback_kernel<<<B / ITEMS_PER_BLOCK, 256, 0, stream>>>(
            x, token_embed, pos_embed, Wq, bq, Wk, bk, Wv, bv, Wo, bo,
            W1, b1, W2, b2, Wh, bh, out);
    }
}